// Round 1
// baseline (401.703 us; speedup 1.0000x reference)
//
#include <hip/hip_runtime.h>

#define BB 8
#define NNODES 1024
#define FIN 64
#define NH 4
#define NC 32
#define HDIM 128          // HIN == HID == 128
#define NEG_INF_F (-1e9f)

#define LOGITS_CNT (BB*NNODES*NNODES*3)   // 25165824
#define HP_OFF LOGITS_CNT

// workspace layout (float offsets)
#define WS_HH    0
#define WS_SSRC  (WS_HH    + BB*NNODES*HDIM)   // [B][N][4]
#define WS_SDSTT (WS_SSRC  + BB*NNODES*NH)     // [B][4][N]
#define WS_M     (WS_SDSTT + BB*NH*NNODES)     // [B][N][4]
#define WS_RSUM  (WS_M     + BB*NNODES*NH)     // [B][N][4]
#define WS_CONV  (WS_RSUM  + BB*NNODES*NH)     // [B][N][128]
#define WS_T     (WS_CONV  + BB*NNODES*HDIM)   // [B][3][N][128]

__device__ __forceinline__ float sigmoidf_(float x) { return 1.0f/(1.0f+__expf(-x)); }
__device__ __forceinline__ float tanhf_(float x) {
  float e = __expf(2.0f*x); return 1.0f - 2.0f/(e+1.0f);
}
__device__ __forceinline__ void ld4(const float* p, float* d) {
  float4 v = *(const float4*)p;
  d[0]=v.x; d[1]=v.y; d[2]=v.z; d[3]=v.w;
}

// ---------------- Kernel A: hh = x@Wk, per-node src/dst scores ----------------
__global__ __launch_bounds__(256) void k_hh_scores(
    const float* __restrict__ x, const float* __restrict__ Wk,
    const float* __restrict__ att_src, const float* __restrict__ att_dst,
    float* __restrict__ ws)
{
  __shared__ float wk_l[FIN*HDIM];   // 64x128 = 32KB
  __shared__ float x_l[8][FIN];      // 2KB
  int tid = threadIdx.x;
  int blk = blockIdx.x;
  int b = blk >> 7;                  // 128 blocks per batch
  int n0 = (blk & 127) * 8;
  #pragma unroll
  for (int t = 0; t < 8; ++t) {
    int idx = tid + t*256;           // float4 index over 2048
    int r = idx >> 5, c4 = idx & 31;
    *(float4*)&wk_l[r*HDIM + c4*4] = *(const float4*)&Wk[r*HDIM + c4*4];
  }
  if (tid < 128) {
    int r = tid >> 4, c4 = tid & 15;
    *(float4*)&x_l[r][c4*4] = *(const float4*)&x[((size_t)(b*NNODES)+n0+r)*FIN + c4*4];
  }
  __syncthreads();
  int col = tid & 127;
  int rh = tid >> 7;
  float as = att_src[col], ad = att_dst[col];
  float acc[4];
  #pragma unroll
  for (int rr = 0; rr < 4; ++rr) acc[rr] = 0.f;
  for (int k = 0; k < FIN; ++k) {
    float wv = wk_l[k*HDIM + col];
    #pragma unroll
    for (int rr = 0; rr < 4; ++rr)
      acc[rr] = fmaf(x_l[rh*4+rr][k], wv, acc[rr]);
  }
  float* hh    = ws + WS_HH;
  float* ssrc  = ws + WS_SSRC;
  float* sdstT = ws + WS_SDSTT;
  int hI = col >> 5;
  #pragma unroll
  for (int rr = 0; rr < 4; ++rr) {
    int n = n0 + rh*4 + rr;
    hh[((size_t)(b*NNODES)+n)*HDIM + col] = acc[rr];
    float ss = acc[rr]*as, sd = acc[rr]*ad;
    #pragma unroll
    for (int m = 16; m >= 1; m >>= 1) {
      ss += __shfl_xor(ss, m, 64);
      sd += __shfl_xor(sd, m, 64);
    }
    if ((col & 31) == 0) {
      ssrc[((size_t)(b*NNODES)+n)*NH + hI] = ss;
      sdstT[(size_t)(b*NH + hI)*NNODES + n] = sd;
    }
  }
}

// ---------------- Kernel B: softmax stats (max, 1/sum) per (b,i,h) ----------------
__global__ __launch_bounds__(256) void k_stats(
    const float* __restrict__ a, float* __restrict__ ws)
{
  __shared__ float a_l[NNODES];  // 4KB
  int tid = threadIdx.x;
  int blk = blockIdx.x;
  int b = blk >> 10, i = blk & 1023;
  const float* arow = a + ((size_t)(b*NNODES + i))*NNODES;
  *(float4*)&a_l[tid*4] = *(const float4*)&arow[tid*4];
  __syncthreads();
  int h = tid >> 6, lane = tid & 63;
  const float* ssrc  = ws + WS_SSRC;
  const float* sdstT = ws + WS_SDSTT;
  float si = ssrc[((size_t)(b*NNODES)+i)*NH + h];
  float e[16];
  float mx = -3.4e38f;
  #pragma unroll
  for (int t = 0; t < 16; ++t) {
    int j = lane + t*64;
    float s = si + sdstT[(size_t)(b*NH+h)*NNODES + j];
    float ev = s >= 0.f ? s : 0.2f*s;
    ev += NEG_INF_F * (1.0f - a_l[j]);
    e[t] = ev;
    mx = fmaxf(mx, ev);
  }
  #pragma unroll
  for (int m = 32; m >= 1; m >>= 1) mx = fmaxf(mx, __shfl_xor(mx, m, 64));
  float sum = 0.f;
  #pragma unroll
  for (int t = 0; t < 16; ++t) sum += __expf(e[t] - mx);
  #pragma unroll
  for (int m = 32; m >= 1; m >>= 1) sum += __shfl_xor(sum, m, 64);
  if (lane == 0) {
    ws[WS_M    + ((size_t)(b*NNODES)+i)*NH + h] = mx;
    ws[WS_RSUM + ((size_t)(b*NNODES)+i)*NH + h] = 1.0f / sum;
  }
}

// ---------------- Kernel C: conv = softmax(e) @ hh, + bias ----------------
#define P_RS 268   // row stride (floats) for p_l: 268 % 32 == 12
#define P_HS 66    // head stride
__global__ __launch_bounds__(256) void k_conv(
    const float* __restrict__ a, const float* __restrict__ bias_gat,
    float* __restrict__ ws)
{
  __shared__ float hh_l[64*HDIM];     // 32KB
  __shared__ float p_l[32*P_RS];      // 34.3KB
  __shared__ float aT[32*64];         // 8KB
  __shared__ float ssrc_l[32*4], m_l[32*4], rs_l[32*4];
  int tid = threadIdx.x;
  int blk = blockIdx.x;
  int b = blk >> 5;
  int i0 = (blk & 31) * 32;
  const float* hh    = ws + WS_HH;
  const float* sdstT = ws + WS_SDSTT;
  if (tid < 128) {
    int r = tid >> 2, h = tid & 3;
    ssrc_l[r*4+h] = ws[WS_SSRC + ((size_t)(b*NNODES)+i0+r)*NH + h];
    m_l[r*4+h]    = ws[WS_M    + ((size_t)(b*NNODES)+i0+r)*NH + h];
    rs_l[r*4+h]   = ws[WS_RSUM + ((size_t)(b*NNODES)+i0+r)*NH + h];
  }
  int jj = tid & 63, hF = tid >> 6;          // phase-1 mapping
  int col4 = tid & 31, rg = tid >> 5;        // phase-2 mapping
  int h2 = col4 >> 3;
  float acc[4][4];
  #pragma unroll
  for (int r = 0; r < 4; ++r)
    #pragma unroll
    for (int c = 0; c < 4; ++c) acc[r][c] = 0.f;
  __syncthreads();
  for (int jt = 0; jt < 16; ++jt) {
    int j0 = jt * 64;
    #pragma unroll
    for (int t = 0; t < 8; ++t) {            // hh chunk [64][128]
      int idx = tid + t*256;
      int r = idx >> 5, c4 = idx & 31;
      *(float4*)&hh_l[r*HDIM + c4*4] =
        *(const float4*)&hh[((size_t)(b*NNODES) + j0 + r)*HDIM + c4*4];
    }
    #pragma unroll
    for (int t = 0; t < 2; ++t) {            // a tile [32][64]
      int idx = tid + t*256;
      int r = idx >> 4, jq = idx & 15;
      *(float4*)&aT[r*64 + jq*4] =
        *(const float4*)&a[((size_t)(b*NNODES) + i0 + r)*NNODES + j0 + jq*4];
    }
    float sd = sdstT[(size_t)(b*NH + hF)*NNODES + j0 + jj];
    __syncthreads();
    // phase 1: p = softmax prob for (row, hF, jj)
    for (int r = 0; r < 32; ++r) {
      float s = ssrc_l[r*4+hF] + sd;
      float ev = s >= 0.f ? s : 0.2f*s;
      ev += NEG_INF_F*(1.0f - aT[r*64 + jj]);
      p_l[r*P_RS + hF*P_HS + jj] = __expf(ev - m_l[r*4+hF]) * rs_l[r*4+hF];
    }
    __syncthreads();
    // phase 2: acc += p * hh
    for (int j = 0; j < 64; ++j) {
      float hv[4];
      ld4(&hh_l[j*HDIM + col4*4], hv);
      #pragma unroll
      for (int rr = 0; rr < 4; ++rr) {
        float pv = p_l[(rg*4+rr)*P_RS + h2*P_HS + j];
        #pragma unroll
        for (int c = 0; c < 4; ++c)
          acc[rr][c] = fmaf(pv, hv[c], acc[rr][c]);
      }
    }
    __syncthreads();
  }
  float bias[4];
  ld4(&bias_gat[col4*4], bias);
  float* conv = ws + WS_CONV;
  #pragma unroll
  for (int rr = 0; rr < 4; ++rr) {
    int n = i0 + rg*4 + rr;
    float4 o;
    o.x = acc[rr][0] + bias[0]; o.y = acc[rr][1] + bias[1];
    o.z = acc[rr][2] + bias[2]; o.w = acc[rr][3] + bias[3];
    *(float4*)&conv[((size_t)(b*NNODES) + n)*HDIM + col4*4] = o;
  }
}

// ---------------- Kernel D: GRU-style gated update -> h_prime ----------------
#define CU_S 260
#define RH_S 132
__global__ __launch_bounds__(256) void k_gru(
    const float* __restrict__ h_in,
    const float* __restrict__ b_u, const float* __restrict__ b_r, const float* __restrict__ b_c,
    const float* __restrict__ W_u, const float* __restrict__ W_r, const float* __restrict__ W_c,
    float* __restrict__ ws, float* __restrict__ out)
{
  __shared__ float cu_l[32*CU_S];   // 33.3KB  [row][256]: conv | h
  __shared__ float rh_l[32*RH_S];   // 16.9KB
  int tid = threadIdx.x;
  int blk = blockIdx.x;
  int b = blk >> 5;
  int i0 = (blk & 31)*32;
  const float* conv = ws + WS_CONV;
  #pragma unroll
  for (int t = 0; t < 8; ++t) {
    int idx = tid + t*256;           // float4 over 2048
    int r = idx >> 6, c4 = idx & 63;
    float4 v;
    if (c4 < 32) v = *(const float4*)&conv[((size_t)(b*NNODES)+i0+r)*HDIM + c4*4];
    else         v = *(const float4*)&h_in[((size_t)(b*NNODES)+i0+r)*HDIM + (c4-32)*4];
    *(float4*)&cu_l[r*CU_S + c4*4] = v;
  }
  __syncthreads();
  int r = tid >> 3, cg = tid & 7;
  int col0 = cg*16;
  float acc[16], uu[16];
  // ---- U gate ----
  #pragma unroll
  for (int c = 0; c < 16; ++c) acc[c] = 0.f;
  for (int k = 0; k < 256; ++k) {
    float cv = cu_l[r*CU_S + k];
    #pragma unroll
    for (int q = 0; q < 4; ++q) {
      float w[4]; ld4(&W_u[k*HDIM + col0 + q*4], w);
      #pragma unroll
      for (int c = 0; c < 4; ++c)
        acc[q*4+c] = fmaf(cv, w[c], acc[q*4+c]);
    }
  }
  float bu_ = b_u[i0 + r];
  #pragma unroll
  for (int c = 0; c < 16; ++c) uu[c] = sigmoidf_(bu_ + acc[c]);
  // ---- R gate ----
  #pragma unroll
  for (int c = 0; c < 16; ++c) acc[c] = 0.f;
  for (int k = 0; k < 256; ++k) {
    float cv = cu_l[r*CU_S + k];
    #pragma unroll
    for (int q = 0; q < 4; ++q) {
      float w[4]; ld4(&W_r[k*HDIM + col0 + q*4], w);
      #pragma unroll
      for (int c = 0; c < 4; ++c)
        acc[q*4+c] = fmaf(cv, w[c], acc[q*4+c]);
    }
  }
  float br_ = b_r[i0 + r];
  #pragma unroll
  for (int c = 0; c < 16; ++c) {
    float rv = sigmoidf_(br_ + acc[c]);
    rh_l[r*RH_S + col0 + c] = rv * cu_l[r*CU_S + 128 + col0 + c];
  }
  __syncthreads();
  // ---- C gate ----
  #pragma unroll
  for (int c = 0; c < 16; ++c) acc[c] = 0.f;
  for (int k = 0; k < 128; ++k) {
    float cv = cu_l[r*CU_S + k];
    #pragma unroll
    for (int q = 0; q < 4; ++q) {
      float w[4]; ld4(&W_c[k*HDIM + col0 + q*4], w);
      #pragma unroll
      for (int c = 0; c < 4; ++c)
        acc[q*4+c] = fmaf(cv, w[c], acc[q*4+c]);
    }
  }
  for (int k = 0; k < 128; ++k) {
    float cv = rh_l[r*RH_S + k];
    #pragma unroll
    for (int q = 0; q < 4; ++q) {
      float w[4]; ld4(&W_c[(128+k)*HDIM + col0 + q*4], w);
      #pragma unroll
      for (int c = 0; c < 4; ++c)
        acc[q*4+c] = fmaf(cv, w[c], acc[q*4+c]);
    }
  }
  float bc_ = b_c[i0 + r];
  #pragma unroll
  for (int q = 0; q < 4; ++q) {
    float res[4];
    #pragma unroll
    for (int c = 0; c < 4; ++c) {
      float cval = tanhf_(bc_ + acc[q*4+c]);
      float hv = cu_l[r*CU_S + 128 + col0 + q*4 + c];
      float u = uu[q*4+c];
      res[c] = u*hv + (1.0f-u)*cval;
    }
    float4 o; o.x=res[0]; o.y=res[1]; o.z=res[2]; o.w=res[3];
    *(float4*)&out[HP_OFF + ((size_t)(b*NNODES)+i0+r)*HDIM + col0 + q*4] = o;
  }
}

// ---------------- Kernel E: T[b][k3] = h' @ R_k3 ----------------
#define HP_S 132
__global__ __launch_bounds__(128) void k_T(
    const float* __restrict__ R_p, const float* __restrict__ R_mu, const float* __restrict__ R_sg,
    const float* __restrict__ out, float* __restrict__ ws)
{
  __shared__ float hp_l[32*HP_S];  // 16.9KB
  int tid = threadIdx.x;
  int blk = blockIdx.x;
  int b = blk / 96;
  int rem = blk % 96;
  int k3 = rem >> 5;
  int n0 = (rem & 31) * 32;
  const float* hp = out + HP_OFF;
  const float* R = (k3 == 0) ? R_p : (k3 == 1) ? R_mu : R_sg;
  #pragma unroll
  for (int t = 0; t < 8; ++t) {
    int idx = tid + t*128;          // float4 over 1024
    int r = idx >> 5, c4 = idx & 31;
    *(float4*)&hp_l[r*HP_S + c4*4] =
      *(const float4*)&hp[((size_t)(b*NNODES)+n0+r)*HDIM + c4*4];
  }
  __syncthreads();
  int cg = tid & 31, rg = tid >> 5;   // cols cg*4..+3, rows rg + 4*rr
  float acc[8][4];
  #pragma unroll
  for (int rr = 0; rr < 8; ++rr)
    #pragma unroll
    for (int c = 0; c < 4; ++c) acc[rr][c] = 0.f;
  for (int k4 = 0; k4 < 32; ++k4) {
    float w[4][4];
    #pragma unroll
    for (int kk = 0; kk < 4; ++kk) ld4(&R[(size_t)(k4*4+kk)*HDIM + cg*4], w[kk]);
    #pragma unroll
    for (int rr = 0; rr < 8; ++rr) {
      float hv[4];
      ld4(&hp_l[(rg + 4*rr)*HP_S + k4*4], hv);
      #pragma unroll
      for (int c = 0; c < 4; ++c) {
        float s = acc[rr][c];
        s = fmaf(hv[0], w[0][c], s);
        s = fmaf(hv[1], w[1][c], s);
        s = fmaf(hv[2], w[2][c], s);
        s = fmaf(hv[3], w[3][c], s);
        acc[rr][c] = s;
      }
    }
  }
  float* T = ws + WS_T;
  #pragma unroll
  for (int rr = 0; rr < 8; ++rr) {
    int row = rg + 4*rr;
    float4 o; o.x=acc[rr][0]; o.y=acc[rr][1]; o.z=acc[rr][2]; o.w=acc[rr][3];
    *(float4*)&T[((size_t)((b*3+k3)*NNODES)+n0+row)*HDIM + cg*4] = o;
  }
}

// ---------------- Kernel F: logits[b,n,m,k3] = T[b,k3,n,:] . h'[b,m,:] ----------------
#define FT_S 132
__global__ __launch_bounds__(256) void k_logits(
    const float* __restrict__ ws, const float* __restrict__ out_hp, float* __restrict__ out)
{
  __shared__ float t_l[64*FT_S];    // 33.8KB
  __shared__ float hp_l[64*FT_S];   // 33.8KB
  int tid = threadIdx.x;
  int blk = blockIdx.x;
  int b = blk >> 8;
  int nt = (blk >> 4) & 15, mt = blk & 15;
  int n0 = nt*64, m0 = mt*64;
  const float* hp = out_hp + HP_OFF;
  const float* T = ws + WS_T;
  #pragma unroll
  for (int t = 0; t < 8; ++t) {
    int idx = tid + t*256;
    int r = idx >> 5, c4 = idx & 31;
    *(float4*)&hp_l[r*FT_S + c4*4] =
      *(const float4*)&hp[((size_t)(b*NNODES)+m0+r)*HDIM + c4*4];
  }
  int ng = tid >> 4, mg = tid & 15;
  for (int k3 = 0; k3 < 3; ++k3) {
    __syncthreads();
    #pragma unroll
    for (int t = 0; t < 8; ++t) {
      int idx = tid + t*256;
      int r = idx >> 5, c4 = idx & 31;
      *(float4*)&t_l[r*FT_S + c4*4] =
        *(const float4*)&T[((size_t)((b*3+k3)*NNODES)+n0+r)*HDIM + c4*4];
    }
    __syncthreads();
    float acc[4][4];
    #pragma unroll
    for (int nn = 0; nn < 4; ++nn)
      #pragma unroll
      for (int mm = 0; mm < 4; ++mm) acc[nn][mm] = 0.f;
    for (int k4 = 0; k4 < 32; ++k4) {
      float tv[4][4], hv[4][4];
      #pragma unroll
      for (int nn = 0; nn < 4; ++nn) ld4(&t_l[(ng*4+nn)*FT_S + k4*4], tv[nn]);
      #pragma unroll
      for (int mm = 0; mm < 4; ++mm) ld4(&hp_l[(mg+16*mm)*FT_S + k4*4], hv[mm]);
      #pragma unroll
      for (int nn = 0; nn < 4; ++nn)
        #pragma unroll
        for (int mm = 0; mm < 4; ++mm) {
          float s = acc[nn][mm];
          s = fmaf(tv[nn][0], hv[mm][0], s);
          s = fmaf(tv[nn][1], hv[mm][1], s);
          s = fmaf(tv[nn][2], hv[mm][2], s);
          s = fmaf(tv[nn][3], hv[mm][3], s);
          acc[nn][mm] = s;
        }
    }
    #pragma unroll
    for (int nn = 0; nn < 4; ++nn) {
      size_t base = ((size_t)(b*NNODES) + n0 + ng*4 + nn)*NNODES;
      #pragma unroll
      for (int mm = 0; mm < 4; ++mm) {
        size_t m = m0 + mg + 16*mm;
        out[(base + m)*3 + k3] = acc[nn][mm];
      }
    }
  }
}

extern "C" void kernel_launch(void* const* d_in, const int* in_sizes, int n_in,
                              void* d_out, int out_size, void* d_ws, size_t ws_size,
                              hipStream_t stream) {
  (void)in_sizes; (void)n_in; (void)out_size; (void)ws_size;
  const float* x        = (const float*)d_in[0];
  const float* a        = (const float*)d_in[1];
  const float* h        = (const float*)d_in[2];
  const float* Wk       = (const float*)d_in[3];
  const float* att_src  = (const float*)d_in[4];
  const float* att_dst  = (const float*)d_in[5];
  const float* bias_gat = (const float*)d_in[6];
  const float* b_u      = (const float*)d_in[7];
  const float* b_r      = (const float*)d_in[8];
  const float* b_c      = (const float*)d_in[9];
  const float* W_u      = (const float*)d_in[10];
  const float* W_r      = (const float*)d_in[11];
  const float* W_c      = (const float*)d_in[12];
  const float* R_p      = (const float*)d_in[13];
  const float* R_mu     = (const float*)d_in[14];
  const float* R_sg     = (const float*)d_in[15];
  float* out = (float*)d_out;
  float* ws  = (float*)d_ws;

  hipLaunchKernelGGL(k_hh_scores, dim3(1024), dim3(256), 0, stream,
                     x, Wk, att_src, att_dst, ws);
  hipLaunchKernelGGL(k_stats, dim3(8192), dim3(256), 0, stream, a, ws);
  hipLaunchKernelGGL(k_conv, dim3(256), dim3(256), 0, stream, a, bias_gat, ws);
  hipLaunchKernelGGL(k_gru, dim3(256), dim3(256), 0, stream,
                     h, b_u, b_r, b_c, W_u, W_r, W_c, ws, out);
  hipLaunchKernelGGL(k_T, dim3(768), dim3(128), 0, stream, R_p, R_mu, R_sg, out, ws);
  hipLaunchKernelGGL(k_logits, dim3(2048), dim3(256), 0, stream, ws, out, out);
}